// Round 2
// baseline (1473.307 us; speedup 1.0000x reference)
//
#include <hip/hip_runtime.h>
#include <hip/hip_bf16.h>

#define NN 50000
#define NE 1600000
#define D  128

// ws layout:
//   [0, 25,600,000)              agg  f32 [NN][D]
//   [25,600,000, 25,800,000)     cnt  u32 [NN]
//   [25,800,000, 25,800,004)     detect flag (int)
#define AGG_BYTES   ((size_t)NN * D * 4)
#define CNT_BYTES   ((size_t)NN * 4)
#define FLAG_OFF    (AGG_BYTES + CNT_BYTES)
#define WS_USED     (FLAG_OFF + 64)

// ---------------------------------------------------------------------------
// Detect whether edge_index arrived as int64 (odd 32-bit words all zero) or
// int32. Writes count of zero odd-words among first 2048 slots into flag.
__global__ __launch_bounds__(256) void k_detect(const int* __restrict__ ei,
                                                int* __restrict__ flag) {
    int local = 0;
    for (int i = threadIdx.x; i < 2048; i += 256)
        if (ei[2 * i + 1] == 0) local++;
    if (local) atomicAdd(flag, local);
}

// ---------------------------------------------------------------------------
// One wave per edge: gather x[src] (512B coalesced), atomic-add into agg[dst].
__global__ __launch_bounds__(256) void k_scatter(const float* __restrict__ x,
                                                 const int* __restrict__ ei,
                                                 float* __restrict__ agg,
                                                 unsigned int* __restrict__ cnt,
                                                 const int* __restrict__ flag) {
    const bool is64 = (*flag > 1024);
    const int lane = threadIdx.x & 63;
    const int wave = (int)((blockIdx.x * 256u + threadIdx.x) >> 6);
    const int nw   = (int)((gridDim.x * 256u) >> 6);
    for (int e = wave; e < NE; e += nw) {
        int src, dst;
        if (is64) { src = ei[2 * e];  dst = ei[2 * (NE + e)]; }
        else      { src = ei[e];      dst = ei[NE + e]; }
        const float2 v = *reinterpret_cast<const float2*>(x + (size_t)src * D + lane * 2);
        float* a = agg + (size_t)dst * D + lane * 2;
        unsafeAtomicAdd(a,     v.x);
        unsafeAtomicAdd(a + 1, v.y);
        if (lane == 0) atomicAdd(cnt + dst, 1u);
    }
}

// ---------------------------------------------------------------------------
// Fused: mean = agg/max(cnt,1); out = relu([mean|x] @ [W_l|W_r]^T + b_l), f32.
// Block: 256 threads = (kk in {0,1}) x (j in 0..127). Thread holds 128 W
// floats in registers; 8 rows of (mean||x) staged in LDS per iteration.
__global__ __launch_bounds__(256) void k_gemm(const float* __restrict__ x,
                                              const float* __restrict__ Wl,
                                              const float* __restrict__ bl,
                                              const float* __restrict__ Wr,
                                              const float* __restrict__ agg,
                                              const unsigned int* __restrict__ cnt,
                                              float* __restrict__ out) {
    __shared__ float rowbuf[8][256];   // 8 rows x (mean[128] || x[128])
    __shared__ float part[8][128];     // kk=1 partial sums

    const int t  = threadIdx.x;
    const int kk = t >> 7;     // which K-half (0: mean/W_l, 1: x/W_r)
    const int j  = t & 127;    // output column

    // Preload this thread's W row (contiguous 128 floats) into registers.
    float w[128];
    const float* wrow = (kk == 0 ? Wl : Wr) + (size_t)j * D;
    #pragma unroll
    for (int k4 = 0; k4 < 32; k4++) {
        float4 v = reinterpret_cast<const float4*>(wrow)[k4];
        w[4 * k4 + 0] = v.x; w[4 * k4 + 1] = v.y;
        w[4 * k4 + 2] = v.z; w[4 * k4 + 3] = v.w;
    }
    const float bias = bl[j];

    const int ngroups = NN / 8;  // 6250 exactly
    for (int g = blockIdx.x; g < ngroups; g += gridDim.x) {
        const int row0 = g * 8;
        // Cooperative load: thread -> (row rr = t>>5, float4 slot q = t&31).
        {
            const int rr  = t >> 5;
            const int q   = t & 31;
            const int row = row0 + rr;
            const float inv = 1.0f / fmaxf((float)cnt[row], 1.0f);
            float4 a  = reinterpret_cast<const float4*>(agg + (size_t)row * D)[q];
            float4 xv = reinterpret_cast<const float4*>(x   + (size_t)row * D)[q];
            a.x *= inv; a.y *= inv; a.z *= inv; a.w *= inv;
            reinterpret_cast<float4*>(&rowbuf[rr][0])[q]   = a;
            reinterpret_cast<float4*>(&rowbuf[rr][128])[q] = xv;
        }
        __syncthreads();

        float acc[8];
        #pragma unroll
        for (int rr = 0; rr < 8; rr++) {
            const float* m = &rowbuf[rr][kk * 128];
            float a = 0.0f;
            #pragma unroll
            for (int k4 = 0; k4 < 32; k4++) {
                float4 v = reinterpret_cast<const float4*>(m)[k4];  // broadcast read
                a += w[4 * k4 + 0] * v.x + w[4 * k4 + 1] * v.y
                   + w[4 * k4 + 2] * v.z + w[4 * k4 + 3] * v.w;
            }
            acc[rr] = a;
        }

        if (kk == 1) {
            #pragma unroll
            for (int rr = 0; rr < 8; rr++) part[rr][j] = acc[rr];
        }
        __syncthreads();
        if (kk == 0) {
            #pragma unroll
            for (int rr = 0; rr < 8; rr++) {
                const int row = row0 + rr;
                float s = acc[rr] + part[rr][j] + bias;
                out[(size_t)row * D + j] = fmaxf(s, 0.0f);
            }
        }
        __syncthreads();
    }
}

// ---------------------------------------------------------------------------
extern "C" void kernel_launch(void* const* d_in, const int* in_sizes, int n_in,
                              void* d_out, int out_size, void* d_ws, size_t ws_size,
                              hipStream_t stream) {
    const float* x  = (const float*)d_in[0];
    const int*   ei = (const int*)  d_in[1];
    const float* Wl = (const float*)d_in[2];
    const float* bl = (const float*)d_in[3];
    const float* Wr = (const float*)d_in[4];

    float*        agg  = (float*)d_ws;
    unsigned int* cnt  = (unsigned int*)((char*)d_ws + AGG_BYTES);
    int*          flag = (int*)((char*)d_ws + FLAG_OFF);
    float*        out  = (float*)d_out;

    hipMemsetAsync(d_ws, 0, WS_USED, stream);
    k_detect<<<1, 256, 0, stream>>>(ei, flag);
    k_scatter<<<4096, 256, 0, stream>>>(x, ei, agg, cnt, flag);
    k_gemm<<<1024, 256, 0, stream>>>(x, Wl, bl, Wr, agg, cnt, out);
}

// Round 3
// 522.984 us; speedup vs baseline: 2.8171x; 2.8171x over previous
//
#include <hip/hip_runtime.h>
#include <hip/hip_bf16.h>

#define NN 50000
#define NE 1600000
#define D  128

typedef unsigned int u32;

// ws layout (bytes):
//   deg  u32[NN]      @ 0
//   flag int          @ 200000
//   off  u32[NN+1]    @ 200064
//   cur  u32[NN]      @ 400128
//   csr  u32[NE]      @ 600192
#define DEG_OFF   0
#define FLAG_OFF  200000
#define OFF_OFF   200064
#define CUR_OFF   400128
#define CSR_OFF   600192
#define MEMSET_BYTES 200064   // deg + flag

// ---------------------------------------------------------------------------
// Detect int64 (odd 32-bit words all zero) vs int32 edge indices.
__global__ __launch_bounds__(256) void k_detect(const int* __restrict__ ei,
                                                int* __restrict__ flag) {
    int local = 0;
    for (int i = threadIdx.x; i < 2048; i += 256)
        if (ei[2 * i + 1] == 0) local++;
    if (local) atomicAdd(flag, local);
}

// ---------------------------------------------------------------------------
// Histogram of destination nodes.
__global__ __launch_bounds__(256) void k_hist(const int* __restrict__ ei,
                                              const int* __restrict__ flag,
                                              u32* __restrict__ deg) {
    const bool is64 = (*flag > 1024);
    const int stride = gridDim.x * 256;
    for (int e = blockIdx.x * 256 + threadIdx.x; e < NE; e += stride) {
        const int dst = is64 ? ei[2 * (NE + e)] : ei[NE + e];
        atomicAdd(&deg[dst], 1u);
    }
}

// ---------------------------------------------------------------------------
// Single-block exclusive scan: off[i] = sum(deg[0..i)), off[NN] = NE; cur=off.
__global__ __launch_bounds__(1024) void k_scan(const u32* __restrict__ deg,
                                               u32* __restrict__ off,
                                               u32* __restrict__ cur) {
    __shared__ u32 sums[1024];
    const int t = threadIdx.x;
    const int C = (NN + 1023) / 1024;  // 49
    const int lo = t * C;
    const int hi = min(lo + C, NN);
    u32 s = 0;
    for (int i = lo; i < hi; i++) s += deg[i];
    sums[t] = s;
    __syncthreads();
    for (int ofs = 1; ofs < 1024; ofs <<= 1) {
        u32 v = (t >= ofs) ? sums[t - ofs] : 0u;
        __syncthreads();
        sums[t] += v;
        __syncthreads();
    }
    u32 run = (t == 0) ? 0u : sums[t - 1];
    for (int i = lo; i < hi; i++) {
        off[i] = run;
        cur[i] = run;
        run += deg[i];
    }
    if (t == 1023) off[NN] = sums[1023];
}

// ---------------------------------------------------------------------------
// Scatter edge sources into CSR slots.
__global__ __launch_bounds__(256) void k_fill(const int* __restrict__ ei,
                                              const int* __restrict__ flag,
                                              u32* __restrict__ cur,
                                              u32* __restrict__ csr) {
    const bool is64 = (*flag > 1024);
    const int stride = gridDim.x * 256;
    for (int e = blockIdx.x * 256 + threadIdx.x; e < NE; e += stride) {
        int src, dst;
        if (is64) { src = ei[2 * e]; dst = ei[2 * (NE + e)]; }
        else      { src = ei[e];     dst = ei[NE + e]; }
        const u32 pos = atomicAdd(&cur[dst], 1u);
        csr[pos] = (u32)src;
    }
}

// ---------------------------------------------------------------------------
// Gather-reduce: one wave per node; mean written to `mean` (= d_out).
__global__ __launch_bounds__(256) void k_gather(const float* __restrict__ x,
                                                const u32* __restrict__ off,
                                                const u32* __restrict__ csr,
                                                float* __restrict__ mean) {
    const int lane = threadIdx.x & 63;
    const int wv = (int)((blockIdx.x * 256u + threadIdx.x) >> 6);
    const int nw = (int)((gridDim.x * 256u) >> 6);
    for (int n = wv; n < NN; n += nw) {
        const int lo = (int)off[n];
        const int hi = (int)off[n + 1];
        float a0 = 0.f, a1 = 0.f, b0 = 0.f, b1 = 0.f;
        int e = lo;
        for (; e + 2 <= hi; e += 2) {
            const int s0 = (int)csr[e];
            const int s1 = (int)csr[e + 1];
            const float2 v0 = *reinterpret_cast<const float2*>(x + (size_t)s0 * D + lane * 2);
            const float2 v1 = *reinterpret_cast<const float2*>(x + (size_t)s1 * D + lane * 2);
            a0 += v0.x; a1 += v0.y; b0 += v1.x; b1 += v1.y;
        }
        if (e < hi) {
            const int s0 = (int)csr[e];
            const float2 v0 = *reinterpret_cast<const float2*>(x + (size_t)s0 * D + lane * 2);
            a0 += v0.x; a1 += v0.y;
        }
        const float inv = (hi > lo) ? 1.0f / (float)(hi - lo) : 0.0f;
        float2 r;
        r.x = (a0 + b0) * inv;
        r.y = (a1 + b1) * inv;
        *reinterpret_cast<float2*>(mean + (size_t)n * D + lane * 2) = r;
    }
}

// ---------------------------------------------------------------------------
// Fused: out = relu(mean @ W_l^T + b_l + x @ W_r^T), f32. mean aliases out:
// each 8-row group is read into LDS before the same rows are overwritten.
__global__ __launch_bounds__(256) void k_gemm(const float* __restrict__ x,
                                              const float* __restrict__ Wl,
                                              const float* __restrict__ bl,
                                              const float* __restrict__ Wr,
                                              const float* __restrict__ mean,
                                              float* __restrict__ out) {
    __shared__ float rowbuf[8][256];   // 8 rows x (mean[128] || x[128])
    __shared__ float part[8][128];     // kk=1 partial sums

    const int t  = threadIdx.x;
    const int kk = t >> 7;     // which K-half (0: mean/W_l, 1: x/W_r)
    const int j  = t & 127;    // output column

    float w[128];
    const float* wrow = (kk == 0 ? Wl : Wr) + (size_t)j * D;
    #pragma unroll
    for (int k4 = 0; k4 < 32; k4++) {
        float4 v = reinterpret_cast<const float4*>(wrow)[k4];
        w[4 * k4 + 0] = v.x; w[4 * k4 + 1] = v.y;
        w[4 * k4 + 2] = v.z; w[4 * k4 + 3] = v.w;
    }
    const float bias = bl[j];

    const int ngroups = NN / 8;  // 6250 exactly
    for (int g = blockIdx.x; g < ngroups; g += gridDim.x) {
        const int row0 = g * 8;
        {
            const int rr  = t >> 5;
            const int q   = t & 31;
            const int row = row0 + rr;
            float4 a  = reinterpret_cast<const float4*>(mean + (size_t)row * D)[q];
            float4 xv = reinterpret_cast<const float4*>(x    + (size_t)row * D)[q];
            reinterpret_cast<float4*>(&rowbuf[rr][0])[q]   = a;
            reinterpret_cast<float4*>(&rowbuf[rr][128])[q] = xv;
        }
        __syncthreads();

        float acc[8];
        #pragma unroll
        for (int rr = 0; rr < 8; rr++) {
            const float* m = &rowbuf[rr][kk * 128];
            float a = 0.0f;
            #pragma unroll
            for (int k4 = 0; k4 < 32; k4++) {
                float4 v = reinterpret_cast<const float4*>(m)[k4];  // broadcast read
                a += w[4 * k4 + 0] * v.x + w[4 * k4 + 1] * v.y
                   + w[4 * k4 + 2] * v.z + w[4 * k4 + 3] * v.w;
            }
            acc[rr] = a;
        }

        if (kk == 1) {
            #pragma unroll
            for (int rr = 0; rr < 8; rr++) part[rr][j] = acc[rr];
        }
        __syncthreads();
        if (kk == 0) {
            #pragma unroll
            for (int rr = 0; rr < 8; rr++) {
                const int row = row0 + rr;
                float s = acc[rr] + part[rr][j] + bias;
                out[(size_t)row * D + j] = fmaxf(s, 0.0f);
            }
        }
        __syncthreads();
    }
}

// ---------------------------------------------------------------------------
extern "C" void kernel_launch(void* const* d_in, const int* in_sizes, int n_in,
                              void* d_out, int out_size, void* d_ws, size_t ws_size,
                              hipStream_t stream) {
    const float* x  = (const float*)d_in[0];
    const int*   ei = (const int*)  d_in[1];
    const float* Wl = (const float*)d_in[2];
    const float* bl = (const float*)d_in[3];
    const float* Wr = (const float*)d_in[4];

    char* ws = (char*)d_ws;
    u32* deg  = (u32*)(ws + DEG_OFF);
    int* flag = (int*)(ws + FLAG_OFF);
    u32* off  = (u32*)(ws + OFF_OFF);
    u32* cur  = (u32*)(ws + CUR_OFF);
    u32* csr  = (u32*)(ws + CSR_OFF);
    float* out = (float*)d_out;

    hipMemsetAsync(d_ws, 0, MEMSET_BYTES, stream);
    k_detect<<<1, 256, 0, stream>>>(ei, flag);
    k_hist  <<<2048, 256, 0, stream>>>(ei, flag, deg);
    k_scan  <<<1, 1024, 0, stream>>>(deg, off, cur);
    k_fill  <<<2048, 256, 0, stream>>>(ei, flag, cur, csr);
    k_gather<<<2048, 256, 0, stream>>>(x, off, csr, out);
    k_gemm  <<<1024, 256, 0, stream>>>(x, Wl, bl, Wr, out, out);
}

// Round 4
// 359.066 us; speedup vs baseline: 4.1032x; 1.4565x over previous
//
#include <hip/hip_runtime.h>
#include <hip/hip_bf16.h>

#define NN 50000
#define NE 1600000
#define D  128

typedef unsigned int u32;

// ws layout (bytes):
//   head u32[NN]   @ 0          (memset 0xFF -> all -1)
//   flag int       @ 200000     (memset 0)
//   next u32[NE]   @ 200064
#define HEAD_OFF  0
#define FLAG_OFF  200000
#define NEXT_OFF  200064

// ---------------------------------------------------------------------------
// Detect int64 (odd 32-bit words all zero) vs int32 edge indices.
__global__ __launch_bounds__(256) void k_detect(const int* __restrict__ ei,
                                                int* __restrict__ flag) {
    int local = 0;
    for (int i = threadIdx.x; i < 2048; i += 256)
        if (ei[2 * i + 1] == 0) local++;
    if (local) atomicAdd(flag, local);
}

// ---------------------------------------------------------------------------
// Linked-list CSR: next[e] = old head[dst]. next[] writes are COALESCED
// (edge-order); atomicExch lands on 200KB L2-resident head[].
__global__ __launch_bounds__(256) void k_link(const int* __restrict__ ei,
                                              const int* __restrict__ flag,
                                              u32* __restrict__ head,
                                              u32* __restrict__ next) {
    const bool is64 = (*flag > 1024);
    const int stride = gridDim.x * 256;
    for (int e = blockIdx.x * 256 + threadIdx.x; e < NE; e += stride) {
        const int dst = is64 ? ei[2 * (size_t)(NE + e)] : ei[NE + e];
        next[e] = atomicExch(&head[dst], (u32)e);
    }
}

// ---------------------------------------------------------------------------
// Gather-reduce: one wave per node walks its chain, accumulating x rows.
// Mean written to `mean` (= d_out). Degree counted during the walk.
__global__ __launch_bounds__(256) void k_gather(const float* __restrict__ x,
                                                const int* __restrict__ ei,
                                                const int* __restrict__ flag,
                                                const u32* __restrict__ head,
                                                const u32* __restrict__ next,
                                                float* __restrict__ mean) {
    const bool is64 = (*flag > 1024);
    const int lane = threadIdx.x & 63;
    const int n = (int)((blockIdx.x * 256u + threadIdx.x) >> 6);
    if (n >= NN) return;

    float a0 = 0.f, a1 = 0.f;
    int cnt = 0;
    u32 e = head[n];
    while (e != 0xFFFFFFFFu) {
        const int src = is64 ? ei[2 * (size_t)e] : ei[e];
        const float2 v = *reinterpret_cast<const float2*>(x + (size_t)src * D + lane * 2);
        a0 += v.x; a1 += v.y;
        cnt++;
        e = next[e];
    }
    const float inv = cnt ? 1.0f / (float)cnt : 0.0f;
    float2 r; r.x = a0 * inv; r.y = a1 * inv;
    *reinterpret_cast<float2*>(mean + (size_t)n * D + lane * 2) = r;
}

// ---------------------------------------------------------------------------
// Fused: out = relu(mean @ W_l^T + b_l + x @ W_r^T), f32. mean aliases out:
// each 8-row group is read into LDS before the same rows are overwritten.
__global__ __launch_bounds__(256) void k_gemm(const float* __restrict__ x,
                                              const float* __restrict__ Wl,
                                              const float* __restrict__ bl,
                                              const float* __restrict__ Wr,
                                              const float* __restrict__ mean,
                                              float* __restrict__ out) {
    __shared__ float rowbuf[8][256];   // 8 rows x (mean[128] || x[128])
    __shared__ float part[8][128];     // kk=1 partial sums

    const int t  = threadIdx.x;
    const int kk = t >> 7;     // which K-half (0: mean/W_l, 1: x/W_r)
    const int j  = t & 127;    // output column

    float w[128];
    const float* wrow = (kk == 0 ? Wl : Wr) + (size_t)j * D;
    #pragma unroll
    for (int k4 = 0; k4 < 32; k4++) {
        float4 v = reinterpret_cast<const float4*>(wrow)[k4];
        w[4 * k4 + 0] = v.x; w[4 * k4 + 1] = v.y;
        w[4 * k4 + 2] = v.z; w[4 * k4 + 3] = v.w;
    }
    const float bias = bl[j];

    const int ngroups = NN / 8;  // 6250 exactly
    for (int g = blockIdx.x; g < ngroups; g += gridDim.x) {
        const int row0 = g * 8;
        {
            const int rr  = t >> 5;
            const int q   = t & 31;
            const int row = row0 + rr;
            float4 a  = reinterpret_cast<const float4*>(mean + (size_t)row * D)[q];
            float4 xv = reinterpret_cast<const float4*>(x    + (size_t)row * D)[q];
            reinterpret_cast<float4*>(&rowbuf[rr][0])[q]   = a;
            reinterpret_cast<float4*>(&rowbuf[rr][128])[q] = xv;
        }
        __syncthreads();

        float acc[8];
        #pragma unroll
        for (int rr = 0; rr < 8; rr++) {
            const float* m = &rowbuf[rr][kk * 128];
            float a = 0.0f;
            #pragma unroll
            for (int k4 = 0; k4 < 32; k4++) {
                float4 v = reinterpret_cast<const float4*>(m)[k4];  // broadcast read
                a += w[4 * k4 + 0] * v.x + w[4 * k4 + 1] * v.y
                   + w[4 * k4 + 2] * v.z + w[4 * k4 + 3] * v.w;
            }
            acc[rr] = a;
        }

        if (kk == 1) {
            #pragma unroll
            for (int rr = 0; rr < 8; rr++) part[rr][j] = acc[rr];
        }
        __syncthreads();
        if (kk == 0) {
            #pragma unroll
            for (int rr = 0; rr < 8; rr++) {
                const int row = row0 + rr;
                float s = acc[rr] + part[rr][j] + bias;
                out[(size_t)row * D + j] = fmaxf(s, 0.0f);
            }
        }
        __syncthreads();
    }
}

// ---------------------------------------------------------------------------
extern "C" void kernel_launch(void* const* d_in, const int* in_sizes, int n_in,
                              void* d_out, int out_size, void* d_ws, size_t ws_size,
                              hipStream_t stream) {
    const float* x  = (const float*)d_in[0];
    const int*   ei = (const int*)  d_in[1];
    const float* Wl = (const float*)d_in[2];
    const float* bl = (const float*)d_in[3];
    const float* Wr = (const float*)d_in[4];

    char* ws = (char*)d_ws;
    u32* head = (u32*)(ws + HEAD_OFF);
    int* flag = (int*)(ws + FLAG_OFF);
    u32* next = (u32*)(ws + NEXT_OFF);
    float* out = (float*)d_out;

    hipMemsetAsync(head, 0xFF, 200000, stream);        // all-ones = end marker
    hipMemsetAsync(flag, 0, 64, stream);
    k_detect<<<1, 256, 0, stream>>>(ei, flag);
    k_link  <<<4096, 256, 0, stream>>>(ei, flag, head, next);
    // one wave per node: 50000 waves = 12500 blocks of 4 waves
    k_gather<<<(NN + 3) / 4, 256, 0, stream>>>(x, ei, flag, head, next, out);
    k_gemm  <<<1024, 256, 0, stream>>>(x, Wl, bl, Wr, out, out);
}

// Round 5
// 277.246 us; speedup vs baseline: 5.3141x; 1.2951x over previous
//
#include <hip/hip_runtime.h>
#include <hip/hip_bf16.h>

#define NN 50000
#define NE 1600000
#define D  128

typedef unsigned int u32;
typedef unsigned short u16;
typedef __attribute__((ext_vector_type(8))) short short8;
typedef __attribute__((ext_vector_type(4))) float f32x4;

// ws layout (bytes):
//   head u32[NN]      @ 0          (memset 0xFF -> all -1)
//   flag int          @ 200000     (memset 0)
//   next u32[NE]      @ 200064
//   xb   bf16[NN*D]   @ 6600064    (12.8 MB)   total 19.4 MB
#define HEAD_OFF  0
#define FLAG_OFF  200000
#define NEXT_OFF  200064
#define XB_OFF    6600064

__device__ __forceinline__ u32 pack2(float a, float b) {   // 2x f32 -> bf16 RNE
    u32 ua = __float_as_uint(a), ub = __float_as_uint(b);
    ua = (ua + 0x7FFFu + ((ua >> 16) & 1u)) >> 16;
    ub = (ub + 0x7FFFu + ((ub >> 16) & 1u)) >> 16;
    return ua | (ub << 16);
}

// ---------------------------------------------------------------------------
__global__ __launch_bounds__(256) void k_detect(const int* __restrict__ ei,
                                                int* __restrict__ flag) {
    int local = 0;
    for (int i = threadIdx.x; i < 2048; i += 256)
        if (ei[2 * i + 1] == 0) local++;
    if (local) atomicAdd(flag, local);
}

// ---------------------------------------------------------------------------
// x (f32) -> xb (bf16, packed 2/word), coalesced.
__global__ __launch_bounds__(256) void k_cast(const float* __restrict__ x,
                                              uint4* __restrict__ xb) {
    const int total = NN * D / 8;  // 800000 uint4 slots
    for (int i = blockIdx.x * 256 + threadIdx.x; i < total; i += gridDim.x * 256) {
        const float4 a = reinterpret_cast<const float4*>(x)[2 * i];
        const float4 b = reinterpret_cast<const float4*>(x)[2 * i + 1];
        uint4 o;
        o.x = pack2(a.x, a.y); o.y = pack2(a.z, a.w);
        o.z = pack2(b.x, b.y); o.w = pack2(b.z, b.w);
        xb[i] = o;
    }
}

// ---------------------------------------------------------------------------
// Linked-list CSR: next[e] = old head[dst]; coalesced next[] writes.
__global__ __launch_bounds__(256) void k_link(const int* __restrict__ ei,
                                              const int* __restrict__ flag,
                                              u32* __restrict__ head,
                                              u32* __restrict__ next) {
    const bool is64 = (*flag > 1024);
    const int stride = gridDim.x * 256;
    for (int e = blockIdx.x * 256 + threadIdx.x; e < NE; e += stride) {
        const int dst = is64 ? ei[2 * (size_t)(NE + e)] : ei[NE + e];
        next[e] = atomicExch(&head[dst], (u32)e);
    }
}

// ---------------------------------------------------------------------------
// Gather-reduce over bf16 x: one wave per node walks its chain.
// Each lane: 1 dword = 2 bf16 per edge (256B/row coalesced). Mean f32 -> d_out.
__global__ __launch_bounds__(256) void k_gather(const u32* __restrict__ xb,
                                                const int* __restrict__ ei,
                                                const int* __restrict__ flag,
                                                const u32* __restrict__ head,
                                                const u32* __restrict__ next,
                                                float* __restrict__ mean) {
    const bool is64 = (*flag > 1024);
    const int lane = threadIdx.x & 63;
    const int n = (int)((blockIdx.x * 256u + threadIdx.x) >> 6);
    if (n >= NN) return;

    float a0 = 0.f, a1 = 0.f;
    int cnt = 0;
    u32 e = head[n];
    while (e != 0xFFFFFFFFu) {
        const int src = is64 ? ei[2 * (size_t)e] : ei[e];
        const u32 v = xb[(size_t)src * 64 + lane];
        a0 += __uint_as_float(v << 16);
        a1 += __uint_as_float(v & 0xFFFF0000u);
        cnt++;
        e = next[e];
    }
    const float inv = cnt ? 1.0f / (float)cnt : 0.0f;
    float2 r; r.x = a0 * inv; r.y = a1 * inv;
    *reinterpret_cast<float2*>(mean + (size_t)n * D + lane * 2) = r;
}

// ---------------------------------------------------------------------------
// MFMA GEMM: out = relu([mean|x] @ [Wl|Wr]^T + bl), K=256, bf16 inputs,
// f32 accumulate. io = d_out: mean read per 16-row group, then overwritten
// (block-local, safe). W staged once per block into XOR-swizzled LDS.
__global__ __launch_bounds__(256) void k_gemm(const float* __restrict__ Wl,
                                              const float* __restrict__ Wr,
                                              const float* __restrict__ bl,
                                              const u32* __restrict__ xb,
                                              float* __restrict__ io) {
    __shared__ u16 Bs[128 * 256];  // [j][k] bf16, byte ^= (j&7)<<4
    __shared__ u16 As[16 * 256];   // [m][k] bf16, byte ^= (m&7)<<4

    const int t = threadIdx.x;

    // ---- stage W: 2 matrices x 2048 ushort8 slots ----
    for (int s = t; s < 4096; s += 256) {
        const int mat = s >> 11;           // uniform across block per iteration
        const int j   = (s >> 4) & 127;
        const int k8  = (s & 15) * 8;
        const float* src = (mat ? Wr : Wl) + (size_t)j * 128 + k8;
        const float4 a = reinterpret_cast<const float4*>(src)[0];
        const float4 b = reinterpret_cast<const float4*>(src)[1];
        uint4 o;
        o.x = pack2(a.x, a.y); o.y = pack2(a.z, a.w);
        o.z = pack2(b.x, b.y); o.w = pack2(b.z, b.w);
        const u32 byte = ((u32)(j * 512 + (mat * 128 + k8) * 2)) ^ ((u32)(j & 7) << 4);
        *reinterpret_cast<uint4*>(reinterpret_cast<char*>(Bs) + byte) = o;
    }

    const int lane = t & 63;
    const int wv   = t >> 6;        // 0..3
    const int m16  = lane & 15;
    const int kg   = lane >> 4;     // 0..3

    for (int g = blockIdx.x; g < NN / 16; g += gridDim.x) {
        const int row0 = g * 16;
        __syncthreads();   // W staged / previous group's As reads done
        {
            // stage A: 16 rows x (mean f32->bf16 | xb bf16)
            const int m  = t >> 4;
            const int k8 = (t & 15) * 8;
            const float* src = io + (size_t)(row0 + m) * D + k8;
            const float4 a = reinterpret_cast<const float4*>(src)[0];
            const float4 b = reinterpret_cast<const float4*>(src)[1];
            uint4 o;
            o.x = pack2(a.x, a.y); o.y = pack2(a.z, a.w);
            o.z = pack2(b.x, b.y); o.w = pack2(b.z, b.w);
            const u32 byte = ((u32)(m * 512 + k8 * 2)) ^ ((u32)(m & 7) << 4);
            *reinterpret_cast<uint4*>(reinterpret_cast<char*>(As) + byte) = o;

            const uint4 xv = *reinterpret_cast<const uint4*>(
                xb + (size_t)(row0 + m) * 64 + (t & 15) * 4);
            const u32 byte2 = ((u32)(m * 512 + (128 + k8) * 2)) ^ ((u32)(m & 7) << 4);
            *reinterpret_cast<uint4*>(reinterpret_cast<char*>(As) + byte2) = xv;
        }
        __syncthreads();

        f32x4 acc0 = {0.f, 0.f, 0.f, 0.f};
        f32x4 acc1 = {0.f, 0.f, 0.f, 0.f};
        const int j0 = wv * 32 + m16;        // B row for tile 0
        const int j1 = j0 + 16;              // B row for tile 1
        #pragma unroll
        for (int ks = 0; ks < 8; ks++) {
            const int k = ks * 32 + kg * 8;
            const u32 ab  = ((u32)(m16 * 512 + k * 2)) ^ ((u32)(m16 & 7) << 4);
            const u32 bb0 = ((u32)(j0  * 512 + k * 2)) ^ ((u32)(j0  & 7) << 4);
            const u32 bb1 = ((u32)(j1  * 512 + k * 2)) ^ ((u32)(j1  & 7) << 4);
            const short8 af  = *reinterpret_cast<const short8*>(reinterpret_cast<const char*>(As) + ab);
            const short8 bf0 = *reinterpret_cast<const short8*>(reinterpret_cast<const char*>(Bs) + bb0);
            const short8 bf1 = *reinterpret_cast<const short8*>(reinterpret_cast<const char*>(Bs) + bb1);
            acc0 = __builtin_amdgcn_mfma_f32_16x16x32_bf16(af, bf0, acc0, 0, 0, 0);
            acc1 = __builtin_amdgcn_mfma_f32_16x16x32_bf16(af, bf1, acc1, 0, 0, 0);
        }

        // epilogue: D[r][c]: r=(lane>>4)*4+i, c=lane&15 within each 16x16 tile
        const float bias0 = bl[wv * 32 + m16];
        const float bias1 = bl[wv * 32 + 16 + m16];
        #pragma unroll
        for (int i = 0; i < 4; i++) {
            const int r = kg * 4 + i;
            float* orow = io + (size_t)(row0 + r) * D;
            orow[wv * 32 + m16]      = fmaxf(acc0[i] + bias0, 0.f);
            orow[wv * 32 + 16 + m16] = fmaxf(acc1[i] + bias1, 0.f);
        }
    }
}

// ---------------------------------------------------------------------------
extern "C" void kernel_launch(void* const* d_in, const int* in_sizes, int n_in,
                              void* d_out, int out_size, void* d_ws, size_t ws_size,
                              hipStream_t stream) {
    const float* x  = (const float*)d_in[0];
    const int*   ei = (const int*)  d_in[1];
    const float* Wl = (const float*)d_in[2];
    const float* bl = (const float*)d_in[3];
    const float* Wr = (const float*)d_in[4];

    char* ws = (char*)d_ws;
    u32*   head = (u32*)(ws + HEAD_OFF);
    int*   flag = (int*)(ws + FLAG_OFF);
    u32*   next = (u32*)(ws + NEXT_OFF);
    u32*   xb   = (u32*)(ws + XB_OFF);
    float* out  = (float*)d_out;

    hipMemsetAsync(head, 0xFF, 200000, stream);
    hipMemsetAsync(flag, 0, 64, stream);
    k_detect<<<1, 256, 0, stream>>>(ei, flag);
    k_cast  <<<2048, 256, 0, stream>>>(x, (uint4*)xb);
    k_link  <<<4096, 256, 0, stream>>>(ei, flag, head, next);
    k_gather<<<(NN + 3) / 4, 256, 0, stream>>>(xb, ei, flag, head, next, out);
    k_gemm  <<<1024, 256, 0, stream>>>(Wl, Wr, bl, xb, out);
}

// Round 6
// 221.682 us; speedup vs baseline: 6.6460x; 1.2506x over previous
//
#include <hip/hip_runtime.h>
#include <hip/hip_bf16.h>

#define NN 50000
#define NE 1600000
#define D  128
#define NIL 0xFFFFFFFFu

typedef unsigned int u32;
typedef unsigned long long u64;
typedef unsigned short u16;
typedef __attribute__((ext_vector_type(8))) short short8;
typedef __attribute__((ext_vector_type(4))) float f32x4;

// ws layout (bytes):
//   head u32[NN*8]  @ 0           (1.6 MB, memset 0xFF)
//   flag int        @ 1600000     (memset 0)
//   node u64[NE]    @ 1600064     (12.8 MB)  {src:lo32, next:hi32}
//   xb   bf16[NN*D] @ 14400064    (12.8 MB)
#define HEAD_OFF  0
#define FLAG_OFF  1600000
#define NODE_OFF  1600064
#define XB_OFF    14400064

__device__ __forceinline__ u32 pack2(float a, float b) {   // 2x f32 -> bf16 RNE
    u32 ua = __float_as_uint(a), ub = __float_as_uint(b);
    ua = (ua + 0x7FFFu + ((ua >> 16) & 1u)) >> 16;
    ub = (ub + 0x7FFFu + ((ub >> 16) & 1u)) >> 16;
    return ua | (ub << 16);
}

// ---------------------------------------------------------------------------
__global__ __launch_bounds__(256) void k_detect(const int* __restrict__ ei,
                                                int* __restrict__ flag) {
    int local = 0;
    for (int i = threadIdx.x; i < 2048; i += 256)
        if (ei[2 * i + 1] == 0) local++;
    if (local) atomicAdd(flag, local);
}

// ---------------------------------------------------------------------------
// x (f32) -> xb (bf16, packed 2/word), coalesced.
__global__ __launch_bounds__(256) void k_cast(const float* __restrict__ x,
                                              uint4* __restrict__ xb) {
    const int total = NN * D / 8;  // 800000 uint4 slots
    for (int i = blockIdx.x * 256 + threadIdx.x; i < total; i += gridDim.x * 256) {
        const float4 a = reinterpret_cast<const float4*>(x)[2 * i];
        const float4 b = reinterpret_cast<const float4*>(x)[2 * i + 1];
        uint4 o;
        o.x = pack2(a.x, a.y); o.y = pack2(a.z, a.w);
        o.z = pack2(b.x, b.y); o.w = pack2(b.z, b.w);
        xb[i] = o;
    }
}

// ---------------------------------------------------------------------------
// 8 sub-chains per node: head[dst*8 + (e&7)]. node[e] = {src, old_head}.
// node[] writes coalesced in edge order; atomicExch on 1.6MB L2-resident head.
__global__ __launch_bounds__(256) void k_link(const int* __restrict__ ei,
                                              const int* __restrict__ flag,
                                              u32* __restrict__ head,
                                              u64* __restrict__ node) {
    const bool is64 = (*flag > 1024);
    const int stride = gridDim.x * 256;
    for (int e = blockIdx.x * 256 + threadIdx.x; e < NE; e += stride) {
        int src, dst;
        if (is64) { src = ei[2 * (size_t)e]; dst = ei[2 * (size_t)(NE + e)]; }
        else      { src = ei[e];             dst = ei[NE + e]; }
        const u32 old = atomicExch(&head[dst * 8 + (e & 7)], (u32)e);
        node[e] = (u64)(u32)src | ((u64)old << 32);
    }
}

// ---------------------------------------------------------------------------
// Gather-reduce: one wave per node walks 8 chains concurrently (8-way MLP).
// Per step: 8 independent node loads (8B broadcast) + 8 independent row loads
// (1 dword/lane). Branch-free: dead chains clamp to index 0, accum predicated.
__global__ __launch_bounds__(256) void k_gather(const u32* __restrict__ xb,
                                                const u64* __restrict__ node,
                                                const u32* __restrict__ head,
                                                float* __restrict__ mean) {
    const int lane = threadIdx.x & 63;
    const int n = (int)((blockIdx.x * 256u + threadIdx.x) >> 6);
    if (n >= NN) return;

    u32 e[8];
    #pragma unroll
    for (int i = 0; i < 8; i++) e[i] = head[n * 8 + i];

    float a0 = 0.f, a1 = 0.f;
    int cnt = 0;

    while ((e[0] & e[1] & e[2] & e[3] & e[4] & e[5] & e[6] & e[7]) != NIL) {
        u64 nd[8];
        u32 v[8];
        #pragma unroll
        for (int i = 0; i < 8; i++) {
            const u32 idx = (e[i] == NIL) ? 0u : e[i];
            nd[i] = node[idx];                       // 8 independent loads
        }
        #pragma unroll
        for (int i = 0; i < 8; i++) {
            const u32 src = (u32)nd[i];
            v[i] = xb[(size_t)src * 64 + lane];      // 8 independent row loads
        }
        #pragma unroll
        for (int i = 0; i < 8; i++) {
            if (e[i] != NIL) {
                a0 += __uint_as_float(v[i] << 16);
                a1 += __uint_as_float(v[i] & 0xFFFF0000u);
                cnt++;
                e[i] = (u32)(nd[i] >> 32);
            }
        }
    }

    const float inv = cnt ? 1.0f / (float)cnt : 0.0f;
    float2 r; r.x = a0 * inv; r.y = a1 * inv;
    *reinterpret_cast<float2*>(mean + (size_t)n * D + lane * 2) = r;
}

// ---------------------------------------------------------------------------
// MFMA GEMM: out = relu([mean|x] @ [Wl|Wr]^T + bl), K=256, bf16 in, f32 acc.
// io = d_out: mean rows read into LDS per 16-row group, then overwritten.
__global__ __launch_bounds__(256) void k_gemm(const float* __restrict__ Wl,
                                              const float* __restrict__ Wr,
                                              const float* __restrict__ bl,
                                              const u32* __restrict__ xb,
                                              float* __restrict__ io) {
    __shared__ u16 Bs[128 * 256];  // [j][k] bf16, byte ^= (j&7)<<4
    __shared__ u16 As[16 * 256];   // [m][k] bf16, byte ^= (m&7)<<4

    const int t = threadIdx.x;

    for (int s = t; s < 4096; s += 256) {
        const int mat = s >> 11;
        const int j   = (s >> 4) & 127;
        const int k8  = (s & 15) * 8;
        const float* src = (mat ? Wr : Wl) + (size_t)j * 128 + k8;
        const float4 a = reinterpret_cast<const float4*>(src)[0];
        const float4 b = reinterpret_cast<const float4*>(src)[1];
        uint4 o;
        o.x = pack2(a.x, a.y); o.y = pack2(a.z, a.w);
        o.z = pack2(b.x, b.y); o.w = pack2(b.z, b.w);
        const u32 byte = ((u32)(j * 512 + (mat * 128 + k8) * 2)) ^ ((u32)(j & 7) << 4);
        *reinterpret_cast<uint4*>(reinterpret_cast<char*>(Bs) + byte) = o;
    }

    const int lane = t & 63;
    const int wv   = t >> 6;
    const int m16  = lane & 15;
    const int kg   = lane >> 4;

    for (int g = blockIdx.x; g < NN / 16; g += gridDim.x) {
        const int row0 = g * 16;
        __syncthreads();
        {
            const int m  = t >> 4;
            const int k8 = (t & 15) * 8;
            const float* src = io + (size_t)(row0 + m) * D + k8;
            const float4 a = reinterpret_cast<const float4*>(src)[0];
            const float4 b = reinterpret_cast<const float4*>(src)[1];
            uint4 o;
            o.x = pack2(a.x, a.y); o.y = pack2(a.z, a.w);
            o.z = pack2(b.x, b.y); o.w = pack2(b.z, b.w);
            const u32 byte = ((u32)(m * 512 + k8 * 2)) ^ ((u32)(m & 7) << 4);
            *reinterpret_cast<uint4*>(reinterpret_cast<char*>(As) + byte) = o;

            const uint4 xv = *reinterpret_cast<const uint4*>(
                xb + (size_t)(row0 + m) * 64 + (t & 15) * 4);
            const u32 byte2 = ((u32)(m * 512 + (128 + k8) * 2)) ^ ((u32)(m & 7) << 4);
            *reinterpret_cast<uint4*>(reinterpret_cast<char*>(As) + byte2) = xv;
        }
        __syncthreads();

        f32x4 acc0 = {0.f, 0.f, 0.f, 0.f};
        f32x4 acc1 = {0.f, 0.f, 0.f, 0.f};
        const int j0 = wv * 32 + m16;
        const int j1 = j0 + 16;
        #pragma unroll
        for (int ks = 0; ks < 8; ks++) {
            const int k = ks * 32 + kg * 8;
            const u32 ab  = ((u32)(m16 * 512 + k * 2)) ^ ((u32)(m16 & 7) << 4);
            const u32 bb0 = ((u32)(j0  * 512 + k * 2)) ^ ((u32)(j0  & 7) << 4);
            const u32 bb1 = ((u32)(j1  * 512 + k * 2)) ^ ((u32)(j1  & 7) << 4);
            const short8 af  = *reinterpret_cast<const short8*>(reinterpret_cast<const char*>(As) + ab);
            const short8 bf0 = *reinterpret_cast<const short8*>(reinterpret_cast<const char*>(Bs) + bb0);
            const short8 bf1 = *reinterpret_cast<const short8*>(reinterpret_cast<const char*>(Bs) + bb1);
            acc0 = __builtin_amdgcn_mfma_f32_16x16x32_bf16(af, bf0, acc0, 0, 0, 0);
            acc1 = __builtin_amdgcn_mfma_f32_16x16x32_bf16(af, bf1, acc1, 0, 0, 0);
        }

        const float bias0 = bl[wv * 32 + m16];
        const float bias1 = bl[wv * 32 + 16 + m16];
        #pragma unroll
        for (int i = 0; i < 4; i++) {
            const int r = kg * 4 + i;
            float* orow = io + (size_t)(row0 + r) * D;
            orow[wv * 32 + m16]      = fmaxf(acc0[i] + bias0, 0.f);
            orow[wv * 32 + 16 + m16] = fmaxf(acc1[i] + bias1, 0.f);
        }
    }
}

// ---------------------------------------------------------------------------
extern "C" void kernel_launch(void* const* d_in, const int* in_sizes, int n_in,
                              void* d_out, int out_size, void* d_ws, size_t ws_size,
                              hipStream_t stream) {
    const float* x  = (const float*)d_in[0];
    const int*   ei = (const int*)  d_in[1];
    const float* Wl = (const float*)d_in[2];
    const float* bl = (const float*)d_in[3];
    const float* Wr = (const float*)d_in[4];

    char* ws = (char*)d_ws;
    u32*   head = (u32*)(ws + HEAD_OFF);
    int*   flag = (int*)(ws + FLAG_OFF);
    u64*   node = (u64*)(ws + NODE_OFF);
    u32*   xb   = (u32*)(ws + XB_OFF);
    float* out  = (float*)d_out;

    hipMemsetAsync(head, 0xFF, 1600000, stream);
    hipMemsetAsync(flag, 0, 64, stream);
    k_detect<<<1, 256, 0, stream>>>(ei, flag);
    k_cast  <<<2048, 256, 0, stream>>>(x, (uint4*)xb);
    k_link  <<<4096, 256, 0, stream>>>(ei, flag, head, node);
    k_gather<<<(NN + 3) / 4, 256, 0, stream>>>(xb, node, head, out);
    k_gemm  <<<1024, 256, 0, stream>>>(Wl, Wr, bl, xb, out);
}

// Round 7
// 209.151 us; speedup vs baseline: 7.0442x; 1.0599x over previous
//
#include <hip/hip_runtime.h>
#include <hip/hip_bf16.h>

#define NN 50000
#define NE 1600000
#define D  128
#define NIL 0xFFFFFFFFu

typedef unsigned int u32;
typedef unsigned long long u64;
typedef unsigned short u16;
typedef __attribute__((ext_vector_type(8))) short short8;
typedef __attribute__((ext_vector_type(4))) float f32x4;
typedef __attribute__((ext_vector_type(2))) float f32x2;

// ws layout (bytes):
//   head u32[NN*8]  @ 0           (1.6 MB, memset 0xFF)
//   flag int        @ 1600000     (memset 0)
//   node u64[NE]    @ 1600064     (12.8 MB)  {src:lo32, next:hi32}
//   xf8  fp8[NN*D]  @ 14400064    (6.4 MB)   e4m3, row = 128 B = 32 dwords
#define HEAD_OFF  0
#define FLAG_OFF  1600000
#define NODE_OFF  1600064
#define XF8_OFF   14400064

__device__ __forceinline__ u32 pack2(float a, float b) {   // 2x f32 -> bf16 RNE
    u32 ua = __float_as_uint(a), ub = __float_as_uint(b);
    ua = (ua + 0x7FFFu + ((ua >> 16) & 1u)) >> 16;
    ub = (ub + 0x7FFFu + ((ub >> 16) & 1u)) >> 16;
    return ua | (ub << 16);
}

// ---------------------------------------------------------------------------
__global__ __launch_bounds__(256) void k_detect(const int* __restrict__ ei,
                                                int* __restrict__ flag) {
    int local = 0;
    for (int i = threadIdx.x; i < 2048; i += 256)
        if (ei[2 * i + 1] == 0) local++;
    if (local) atomicAdd(flag, local);
}

// ---------------------------------------------------------------------------
// x (f32) -> xf8 (fp8 e4m3, 4/word), coalesced. 8 floats -> uint2 per slot.
__global__ __launch_bounds__(256) void k_cast(const float* __restrict__ x,
                                              uint2* __restrict__ xf8) {
    const int total = NN * D / 8;  // 800000
    for (int i = blockIdx.x * 256 + threadIdx.x; i < total; i += gridDim.x * 256) {
        const float4 a = reinterpret_cast<const float4*>(x)[2 * i];
        const float4 b = reinterpret_cast<const float4*>(x)[2 * i + 1];
        uint2 o;
        o.x = (u32)__builtin_amdgcn_cvt_pk_fp8_f32(a.z, a.w,
                 __builtin_amdgcn_cvt_pk_fp8_f32(a.x, a.y, 0, false), true);
        o.y = (u32)__builtin_amdgcn_cvt_pk_fp8_f32(b.z, b.w,
                 __builtin_amdgcn_cvt_pk_fp8_f32(b.x, b.y, 0, false), true);
        xf8[i] = o;
    }
}

// ---------------------------------------------------------------------------
// 8 sub-chains per node: head[dst*8 + (e&7)]. node[e] = {src, old_head}.
__global__ __launch_bounds__(256) void k_link(const int* __restrict__ ei,
                                              const int* __restrict__ flag,
                                              u32* __restrict__ head,
                                              u64* __restrict__ node) {
    const bool is64 = (*flag > 1024);
    const int stride = gridDim.x * 256;
    for (int e = blockIdx.x * 256 + threadIdx.x; e < NE; e += stride) {
        int src, dst;
        if (is64) { src = ei[2 * (size_t)e]; dst = ei[2 * (size_t)(NE + e)]; }
        else      { src = ei[e];             dst = ei[NE + e]; }
        const u32 old = atomicExch(&head[dst * 8 + (e & 7)], (u32)e);
        node[e] = (u64)(u32)src | ((u64)old << 32);
    }
}

// ---------------------------------------------------------------------------
// Gather-reduce: one wave per node, 8 chains, 2 edges per row-load instruction
// (lanes 0-31 = chain 2p, lanes 32-63 = chain 2p+1; fp8 row = 32 dwords).
__global__ __launch_bounds__(256) void k_gather(const u32* __restrict__ xf8,
                                                const u64* __restrict__ node,
                                                const u32* __restrict__ head,
                                                float* __restrict__ mean) {
    const int lane = threadIdx.x & 63;
    const int half = lane >> 5;       // 0: even chains, 1: odd chains
    const int q    = lane & 31;       // dword slot within row
    const int n = (int)((blockIdx.x * 256u + threadIdx.x) >> 6);
    if (n >= NN) return;

    u32 e[8];
    #pragma unroll
    for (int i = 0; i < 8; i++) e[i] = head[n * 8 + i];

    float acc0 = 0.f, acc1 = 0.f, acc2 = 0.f, acc3 = 0.f;
    int cnt = 0;

    for (;;) {
        u32 anyAlive = 0;
        #pragma unroll
        for (int i = 0; i < 8; i++) anyAlive |= (e[i] != NIL);
        if (!anyAlive) break;

        u64 nd[8];
        #pragma unroll
        for (int i = 0; i < 8; i++) {
            const u32 idx = (e[i] == NIL) ? 0u : e[i];
            nd[i] = node[idx];                         // 8 independent loads
        }

        #pragma unroll
        for (int p = 0; p < 4; p++) {
            const u32 srcA = (u32)nd[2 * p];
            const u32 srcB = (u32)nd[2 * p + 1];
            const u32 src  = half ? srcB : srcA;       // per-half select
            const bool aliveA = (e[2 * p]     != NIL);
            const bool aliveB = (e[2 * p + 1] != NIL);
            const bool alive  = half ? aliveB : aliveA;
            u32 w = xf8[(size_t)src * 32 + q];         // 2 edges per load
            w = alive ? w : 0u;                        // fp8 0x00 == 0.0f
            const f32x2 lo = __builtin_amdgcn_cvt_pk_f32_fp8((int)w, false);
            const f32x2 hi = __builtin_amdgcn_cvt_pk_f32_fp8((int)w, true);
            acc0 += lo.x; acc1 += lo.y; acc2 += hi.x; acc3 += hi.y;
        }

        #pragma unroll
        for (int i = 0; i < 8; i++) {
            const bool alive = (e[i] != NIL);
            cnt += alive ? 1 : 0;
            e[i] = alive ? (u32)(nd[i] >> 32) : NIL;
        }
    }

    // fold the two halves (each dim accumulated in both half-waves)
    acc0 += __shfl_xor(acc0, 32);
    acc1 += __shfl_xor(acc1, 32);
    acc2 += __shfl_xor(acc2, 32);
    acc3 += __shfl_xor(acc3, 32);

    const float inv = cnt ? 1.0f / (float)cnt : 0.0f;
    if (half == 0) {
        float4 r;
        r.x = acc0 * inv; r.y = acc1 * inv; r.z = acc2 * inv; r.w = acc3 * inv;
        *reinterpret_cast<float4*>(mean + (size_t)n * D + q * 4) = r;
    }
}

// ---------------------------------------------------------------------------
// MFMA GEMM: out = relu([mean|x] @ [Wl|Wr]^T + bl), K=256, bf16 in, f32 acc.
// io = d_out: mean rows read into LDS per 16-row group, then overwritten.
// x staged directly from f32 input.
__global__ __launch_bounds__(256) void k_gemm(const float* __restrict__ Wl,
                                              const float* __restrict__ Wr,
                                              const float* __restrict__ bl,
                                              const float* __restrict__ x,
                                              float* __restrict__ io) {
    __shared__ u16 Bs[128 * 256];  // [j][k] bf16, byte ^= (j&7)<<4
    __shared__ u16 As[16 * 256];   // [m][k] bf16, byte ^= (m&7)<<4

    const int t = threadIdx.x;

    for (int s = t; s < 4096; s += 256) {
        const int mat = s >> 11;
        const int j   = (s >> 4) & 127;
        const int k8  = (s & 15) * 8;
        const float* src = (mat ? Wr : Wl) + (size_t)j * 128 + k8;
        const float4 a = reinterpret_cast<const float4*>(src)[0];
        const float4 b = reinterpret_cast<const float4*>(src)[1];
        uint4 o;
        o.x = pack2(a.x, a.y); o.y = pack2(a.z, a.w);
        o.z = pack2(b.x, b.y); o.w = pack2(b.z, b.w);
        const u32 byte = ((u32)(j * 512 + (mat * 128 + k8) * 2)) ^ ((u32)(j & 7) << 4);
        *reinterpret_cast<uint4*>(reinterpret_cast<char*>(Bs) + byte) = o;
    }

    const int lane = t & 63;
    const int wv   = t >> 6;
    const int m16  = lane & 15;
    const int kg   = lane >> 4;

    for (int g = blockIdx.x; g < NN / 16; g += gridDim.x) {
        const int row0 = g * 16;
        __syncthreads();
        {
            const int m  = t >> 4;
            const int k8 = (t & 15) * 8;
            // mean half (from io)
            const float* srcm = io + (size_t)(row0 + m) * D + k8;
            float4 a = reinterpret_cast<const float4*>(srcm)[0];
            float4 b = reinterpret_cast<const float4*>(srcm)[1];
            uint4 o;
            o.x = pack2(a.x, a.y); o.y = pack2(a.z, a.w);
            o.z = pack2(b.x, b.y); o.w = pack2(b.z, b.w);
            const u32 byte = ((u32)(m * 512 + k8 * 2)) ^ ((u32)(m & 7) << 4);
            *reinterpret_cast<uint4*>(reinterpret_cast<char*>(As) + byte) = o;
            // x half (from f32 input)
            const float* srcx = x + (size_t)(row0 + m) * D + k8;
            a = reinterpret_cast<const float4*>(srcx)[0];
            b = reinterpret_cast<const float4*>(srcx)[1];
            o.x = pack2(a.x, a.y); o.y = pack2(a.z, a.w);
            o.z = pack2(b.x, b.y); o.w = pack2(b.z, b.w);
            const u32 byte2 = ((u32)(m * 512 + (128 + k8) * 2)) ^ ((u32)(m & 7) << 4);
            *reinterpret_cast<uint4*>(reinterpret_cast<char*>(As) + byte2) = o;
        }
        __syncthreads();

        f32x4 acc0 = {0.f, 0.f, 0.f, 0.f};
        f32x4 acc1 = {0.f, 0.f, 0.f, 0.f};
        const int j0 = wv * 32 + m16;
        const int j1 = j0 + 16;
        #pragma unroll
        for (int ks = 0; ks < 8; ks++) {
            const int k = ks * 32 + kg * 8;
            const u32 ab  = ((u32)(m16 * 512 + k * 2)) ^ ((u32)(m16 & 7) << 4);
            const u32 bb0 = ((u32)(j0  * 512 + k * 2)) ^ ((u32)(j0  & 7) << 4);
            const u32 bb1 = ((u32)(j1  * 512 + k * 2)) ^ ((u32)(j1  & 7) << 4);
            const short8 af  = *reinterpret_cast<const short8*>(reinterpret_cast<const char*>(As) + ab);
            const short8 bf0 = *reinterpret_cast<const short8*>(reinterpret_cast<const char*>(Bs) + bb0);
            const short8 bf1 = *reinterpret_cast<const short8*>(reinterpret_cast<const char*>(Bs) + bb1);
            acc0 = __builtin_amdgcn_mfma_f32_16x16x32_bf16(af, bf0, acc0, 0, 0, 0);
            acc1 = __builtin_amdgcn_mfma_f32_16x16x32_bf16(af, bf1, acc1, 0, 0, 0);
        }

        const float bias0 = bl[wv * 32 + m16];
        const float bias1 = bl[wv * 32 + 16 + m16];
        #pragma unroll
        for (int i = 0; i < 4; i++) {
            const int r = kg * 4 + i;
            float* orow = io + (size_t)(row0 + r) * D;
            orow[wv * 32 + m16]      = fmaxf(acc0[i] + bias0, 0.f);
            orow[wv * 32 + 16 + m16] = fmaxf(acc1[i] + bias1, 0.f);
        }
    }
}

// ---------------------------------------------------------------------------
extern "C" void kernel_launch(void* const* d_in, const int* in_sizes, int n_in,
                              void* d_out, int out_size, void* d_ws, size_t ws_size,
                              hipStream_t stream) {
    const float* x  = (const float*)d_in[0];
    const int*   ei = (const int*)  d_in[1];
    const float* Wl = (const float*)d_in[2];
    const float* bl = (const float*)d_in[3];
    const float* Wr = (const float*)d_in[4];

    char* ws = (char*)d_ws;
    u32*   head = (u32*)(ws + HEAD_OFF);
    int*   flag = (int*)(ws + FLAG_OFF);
    u64*   node = (u64*)(ws + NODE_OFF);
    u32*   xf8  = (u32*)(ws + XF8_OFF);
    float* out  = (float*)d_out;

    hipMemsetAsync(head, 0xFF, 1600000, stream);
    hipMemsetAsync(flag, 0, 64, stream);
    k_detect<<<1, 256, 0, stream>>>(ei, flag);
    k_cast  <<<2048, 256, 0, stream>>>(x, (uint2*)xf8);
    k_link  <<<4096, 256, 0, stream>>>(ei, flag, head, node);
    k_gather<<<(NN + 3) / 4, 256, 0, stream>>>(xf8, node, head, out);
    k_gemm  <<<1024, 256, 0, stream>>>(Wl, Wr, bl, x, out);
}